// Round 2
// baseline (27059.683 us; speedup 1.0000x reference)
//
#include <hip/hip_runtime.h>
#include <hip/hip_cooperative_groups.h>
#include <math.h>

namespace cg = cooperative_groups;

#define HH 384
#define WW 512
#define HW 196608            // 384*512
#define QHW 49152            // HW/4
#define CHW 983040           // 5*HW
#define NTOT 7864320         // 8*CHW
#define FLOW_N 3145728       // 8*2*HW
#define NQUADS 393216        // 8*QHW
#define OUT_FLOW_OFF 16
#define OUT_IMG_OFF (16 + FLOW_N)
#define EPS_F 1e-5f
#define EPS_S (1e-5f / 6400.0f)   // smooth-term eps in raw-x domain (S is deg-1 homog in 80x)
#define INV_HW (1.0f/196608.0f)

// single-instruction HW ops (~1 ulp); med3 == min(max(x,lo),hi) for finite x
__device__ __forceinline__ float rsq_f(float x)  { return __builtin_amdgcn_rsqf(x); }
__device__ __forceinline__ float ln_f(float x)   { return 0.69314718055994531f * __builtin_amdgcn_logf(x); }
__device__ __forceinline__ float sqrt_f(float x) { return __builtin_amdgcn_sqrtf(x); }
__device__ __forceinline__ float med3(float x, float lo, float hi) {
  return __builtin_amdgcn_fmed3f(x, lo, hi);
}

// ---- JAX threefry2x32 (bit-exact integer path), host+device ----
__host__ __device__ __forceinline__ void tf2x32(unsigned k0, unsigned k1,
                                                unsigned x0, unsigned x1,
                                                unsigned& o0, unsigned& o1) {
  const unsigned ks2 = k0 ^ k1 ^ 0x1BD11BDAu;
  x0 += k0; x1 += k1;
#define TFR(r) x0 += x1; x1 = (x1 << (r)) | (x1 >> (32 - (r))); x1 ^= x0;
  TFR(13) TFR(15) TFR(26) TFR(6)
  x0 += k1;  x1 += ks2 + 1u;
  TFR(17) TFR(29) TFR(16) TFR(24)
  x0 += ks2; x1 += k0 + 2u;
  TFR(13) TFR(15) TFR(26) TFR(6)
  x0 += k0;  x1 += k1 + 3u;
  TFR(17) TFR(29) TFR(16) TFR(24)
  x0 += k1;  x1 += ks2 + 4u;
  TFR(13) TFR(15) TFR(26) TFR(6)
  x0 += ks2; x1 += k0 + 5u;
#undef TFR
  o0 = x0; o1 = x1;
}

// bits -> NOISE_STD * sqrt(2) * erfinv(uniform(lo,1))   (JAX normal * 0.05)
__device__ __forceinline__ float noise_from_bits(unsigned bits) {
  const float LO = -0.99999994f;                    // nextafter(-1,0)
  float f = __uint_as_float((bits >> 9) | 0x3F800000u) - 1.0f;  // [0,1)
  float u = fmaxf(LO, f * 2.0f + LO);               // (hi-lo) rounds to 2.0f
  // -log1p(-u^2) via factored form (accurate near |u|~1) + HW log
  float w = -ln_f((1.0f - u) * (1.0f + u));
  float p;
  if (w < 5.0f) {
    w -= 2.5f;
    p = 2.81022636e-08f;
    p = p * w + 3.43273939e-07f;
    p = p * w + -3.5233877e-06f;
    p = p * w + -4.39150654e-06f;
    p = p * w + 0.00021858087f;
    p = p * w + -0.00125372503f;
    p = p * w + -0.00417768164f;
    p = p * w + 0.246640727f;
    p = p * w + 1.50140941f;
  } else {
    w = sqrt_f(w) - 3.0f;
    p = -0.000200214257f;
    p = p * w + 0.000100950558f;
    p = p * w + 0.00134934322f;
    p = p * w + -0.00367342844f;
    p = p * w + 0.00573950773f;
    p = p * w + -0.0076224613f;
    p = p * w + 0.00943887047f;
    p = p * w + 1.00167406f;
    p = p * w + 2.83297682f;
  }
  float z = 1.4142135623730951f * (p * u);
  return 0.05f * z;
}

__device__ __forceinline__ float upd(float x, float g) {
  g = med3(g, -0.03f, 0.03f);
  return med3(x - 10.0f * g, -1.0f, 1.0f);
}

// EXACT JAX partitionable-threefry bits: counter = (0, idx), output o0^o1.
__device__ __forceinline__ float noise_at(unsigned ka, unsigned kb, unsigned idx) {
  unsigned o0, o1;
  tf2x32(ka, kb, 0u, idx, o0, o1);
  return noise_from_bits(o0 ^ o1);
}

__device__ __forceinline__ float clip1(float x) { return med3(x, -1.0f, 1.0f); }

// add noise to 4 results and store as float4 (non-final path)
__device__ __forceinline__ void noise_store4(float* dst, const float xn[4],
                                             unsigned ka, unsigned kb, unsigned idx0) {
  float r[4];
#pragma unroll
  for (int j = 0; j < 4; ++j)
    r[j] = clip1(xn[j] + noise_at(ka, kb, idx0 + (unsigned)j));
  *(float4*)dst = make_float4(r[0], r[1], r[2], r[3]);
}

// ---- flow grad step, one 4-px quad (verbatim round-0 math) ----
__device__ __forceinline__ void flow_quad(const float* __restrict__ X,
    float* __restrict__ Y, float s1v, unsigned ka, unsigned kb,
    int b, int q, bool fin) {
  int p = q * 4;                              // pixel base, multiple of 4
  int h = p >> 9, w = p & 511;
  const float* F0 = X + b * 2 * HW;
  const float* F1 = F0 + HW;
  const bool wpos = (w > 0), wend = (w == 508);
  const bool hpos = (h > 0), hlast = (h == 383);

  // ---- stencil values; cf[c][4] duplicated at right edge so dx=0 ----
  float cf[2][5], fm1[2], dw[2][4], dwm1[2], uf[2][5];
  {
    float4 a0 = *(const float4*)(F0 + p);
    float4 a1 = *(const float4*)(F1 + p);
    cf[0][0]=a0.x; cf[0][1]=a0.y; cf[0][2]=a0.z; cf[0][3]=a0.w;
    cf[1][0]=a1.x; cf[1][1]=a1.y; cf[1][2]=a1.z; cf[1][3]=a1.w;
    cf[0][4] = wend ? cf[0][3] : F0[p + 4];
    cf[1][4] = wend ? cf[1][3] : F1[p + 4];
    fm1[0] = wpos ? F0[p - 1] : cf[0][0];
    fm1[1] = wpos ? F1[p - 1] : cf[1][0];
    if (!hlast) {
      float4 d0 = *(const float4*)(F0 + p + WW);
      float4 d1 = *(const float4*)(F1 + p + WW);
      dw[0][0]=d0.x; dw[0][1]=d0.y; dw[0][2]=d0.z; dw[0][3]=d0.w;
      dw[1][0]=d1.x; dw[1][1]=d1.y; dw[1][2]=d1.z; dw[1][3]=d1.w;
      dwm1[0] = wpos ? F0[p + WW - 1] : fm1[0];
      dwm1[1] = wpos ? F1[p + WW - 1] : fm1[1];
    } else {
#pragma unroll
      for (int c = 0; c < 2; ++c) {
        for (int j = 0; j < 4; ++j) dw[c][j] = cf[c][j];   // dy = 0
        dwm1[c] = fm1[c];
      }
    }
    if (hpos) {
      float4 u0 = *(const float4*)(F0 + p - WW);
      float4 u1 = *(const float4*)(F1 + p - WW);
      uf[0][0]=u0.x; uf[0][1]=u0.y; uf[0][2]=u0.z; uf[0][3]=u0.w;
      uf[1][0]=u1.x; uf[1][1]=u1.y; uf[1][2]=u1.z; uf[1][3]=u1.w;
      uf[0][4] = wend ? uf[0][3] : F0[p - WW + 4];
      uf[1][4] = wend ? uf[1][3] : F1[p - WW + 4];
    } else {
#pragma unroll
      for (int c = 0; c < 2; ++c)
        for (int j = 0; j < 5; ++j) uf[c][j] = cf[c][j];   // unused (masked by hpos)
    }
  }

  // ---- shared S sites: SL = S(h,w-1); Sc[j] = S(h,w+j); Su[j] = S(h-1,w+j) ----
  float dxc[2][4], dyc[2][4], invSc[4], dxu[2][4], dyu[2][4], invSu[4];
  float dxl[2], dyl[2], invSL;
#pragma unroll
  for (int j = 0; j < 4; ++j) {
#pragma unroll
    for (int c = 0; c < 2; ++c) {
      dxc[c][j] = cf[c][j + 1] - cf[c][j];
      dyc[c][j] = dw[c][j] - cf[c][j];
      dxu[c][j] = uf[c][j + 1] - uf[c][j];
      dyu[c][j] = cf[c][j] - uf[c][j];
    }
    invSc[j] = rsq_f(dxc[0][j]*dxc[0][j] + dxc[1][j]*dxc[1][j]
                   + dyc[0][j]*dyc[0][j] + dyc[1][j]*dyc[1][j] + EPS_S);
    invSu[j] = rsq_f(dxu[0][j]*dxu[0][j] + dxu[1][j]*dxu[1][j]
                   + dyu[0][j]*dyu[0][j] + dyu[1][j]*dyu[1][j] + EPS_S);
  }
  dxl[0] = cf[0][0] - fm1[0];  dxl[1] = cf[1][0] - fm1[1];
  dyl[0] = dwm1[0] - fm1[0];   dyl[1] = dwm1[1] - fm1[1];
  invSL = rsq_f(dxl[0]*dxl[0] + dxl[1]*dxl[1]
              + dyl[0]*dyl[0] + dyl[1]*dyl[1] + EPS_S);

  // ---- grads + update ----
  float xnF[2][4];
#pragma unroll
  for (int j = 0; j < 4; ++j) {
#pragma unroll
    for (int c = 0; c < 2; ++c) {
      float g = -(dxc[c][j] + dyc[c][j]) * invSc[j];
      if (j == 0) { if (wpos) g += dxl[c] * invSL; }
      else        { g += dxc[c][j - 1] * invSc[j - 1]; }
      if (hpos)   { g += dyu[c][j] * invSu[j]; }
      xnF[c][j] = upd(cf[c][j], g * s1v);
    }
  }

  // ---- noise + store (or final transform) ----
  if (!fin) {
    int nbase = b * CHW + p;                 // noise index in original 5-ch layout
    int sb = b * 2 * HW + p;                 // compact store index
    noise_store4(Y + sb,      xnF[0], ka, kb, (unsigned)nbase);
    noise_store4(Y + sb + HW, xnF[1], ka, kb, (unsigned)(nbase + HW));
  } else {
    float* outF = Y + OUT_FLOW_OFF + b * 2 * HW;
    *(float4*)(outF + p)      = make_float4(xnF[0][0]*80.f, xnF[0][1]*80.f,
                                            xnF[0][2]*80.f, xnF[0][3]*80.f);
    *(float4*)(outF + HW + p) = make_float4(xnF[1][0]*80.f, xnF[1][1]*80.f,
                                            xnF[1][2]*80.f, xnF[1][3]*80.f);
  }
}

// ---- kernels ----
__global__ void k_init(double* acc, float* sw, const float* lw) {
  int t = threadIdx.x;
  if (t < 32) acc[t] = 0.0;
  if (t == 32) {
    sw[0] = expf(lw[0]) * INV_HW * 0.5f;    // data-term scale
    sw[1] = expf(lw[1]) * INV_HW * 80.0f;   // smooth-term scale (incl d(flow)/dx = 80)
  }
}

// ---- persistent cooperative flow kernel: noise0 + 199 noisy steps + final ----
__global__ __launch_bounds__(256) void k_flow_coop(
    const float* __restrict__ init, float* __restrict__ bA, float* __restrict__ bB,
    float* __restrict__ out, const float* __restrict__ sw,
    const unsigned* __restrict__ Kg) {
  cg::grid_group grid = cg::this_grid();
  const int NT = (int)(gridDim.x * 256u);
  const int tid = (int)(blockIdx.x * 256u + threadIdx.x);
  float s1v = sw[1];

  // step "-1": initial noise, compact (B,2,H,W), exact round-0 indexing
  {
    unsigned ka = Kg[0], kb = Kg[1];
    for (int e = tid; e < FLOW_N; e += NT) {
      int b = e / (2 * HW);
      int r = e - b * 2 * HW;
      int orig = b * CHW + r;                // original element index (channels 0..1)
      bB[e] = clip1(init[orig] + noise_at(ka, kb, (unsigned)orig));
    }
  }

  for (int t = 0; t < 200; ++t) {
    grid.sync();
    const bool fin = (t == 199);
    const float* src = (t & 1) ? bA : bB;    // even t: bB -> bA (matches round-0 parity)
    float* dst = fin ? out : ((t & 1) ? bB : bA);
    unsigned ka = 0, kb = 0;
    if (!fin) { ka = Kg[2 * t + 2]; kb = Kg[2 * t + 3]; }
    for (int q0 = tid; q0 < NQUADS; q0 += NT) {
      int b = q0 / QHW;
      int q = q0 - b * QHW;
      flow_quad(src, dst, s1v, ka, kb, b, q, fin);
    }
  }
}

// ---- fallback path (identical to round-0): per-step launches ----
__global__ __launch_bounds__(256) void k_fnoise0(const float* __restrict__ init,
    float* __restrict__ Y, unsigned ka, unsigned kb) {
  int e = blockIdx.x * 256 + threadIdx.x;    // [0, FLOW_N)
  int b = e / (2 * HW);
  int r = e - b * 2 * HW;
  int orig = b * CHW + r;
  Y[e] = clip1(init[orig] + noise_at(ka, kb, (unsigned)orig));
}

template <bool FINAL>
__global__ __launch_bounds__(256) void k_fstep4(const float* __restrict__ X,
    float* __restrict__ Y, const float* __restrict__ sw,
    unsigned ka, unsigned kb) {
  int tid = blockIdx.x * 256 + threadIdx.x;   // [0, NQUADS)
  int b = tid / QHW;
  int q = tid - b * QHW;
  flow_quad(X, Y, sw[1], ka, kb, b, q, FINAL);
}

// img channels: per-pixel independent 200-step recurrence, state in registers.
// 2 pixels/thread -> 6 independent threefry chains (ILP), bits per value EXACT
// (tf(key,0,idx), o0^o1 -- identical to round-0). Keys prefetched from LDS.
__global__ __launch_bounds__(256, 8) void k_img(const float* __restrict__ init,
    const float* __restrict__ in2, const float* __restrict__ sw,
    float* __restrict__ out) {
  __shared__ unsigned Kl[404];
  int tid = threadIdx.x;
  if (tid < 202) {                            // split(key(1),200): tf(0,1,0,t); 2 pad
    unsigned a, bb;
    tf2x32(0u, 1u, 0u, (unsigned)tid, a, bb);
    Kl[2 * tid] = a; Kl[2 * tid + 1] = bb;
  }
  __syncthreads();
  int g = blockIdx.x * 256 + tid;             // [0, 8*HW/2)
  int b = g / (HW / 2);
  int p = (g - b * (HW / 2)) * 2;             // even pixel; pair = (p, p+1)
  float s0 = sw[0];
  unsigned base = (unsigned)(b * CHW + 2 * HW + p);   // channel-2 noise index, pixel A

  float2 v0 = *(const float2*)(init + base);
  float2 v1 = *(const float2*)(init + base + HW);
  float2 v2 = *(const float2*)(init + base + 2 * HW);
  float xA0 = v0.x, xA1 = v1.x, xA2 = v2.x;
  float xB0 = v0.y, xB1 = v1.y, xB2 = v2.y;

  const float* I2 = in2 + b * 3 * HW + p;
  float2 w0 = *(const float2*)(I2);
  float2 w1 = *(const float2*)(I2 + HW);
  float2 w2 = *(const float2*)(I2 + 2 * HW);
  float iA0 = ((w0.x * 2.0f - 1.0f) + 1.0f) * 0.5f;
  float iB0 = ((w0.y * 2.0f - 1.0f) + 1.0f) * 0.5f;
  float iA1 = ((w1.x * 2.0f - 1.0f) + 1.0f) * 0.5f;
  float iB1 = ((w1.y * 2.0f - 1.0f) + 1.0f) * 0.5f;
  float iA2 = ((w2.x * 2.0f - 1.0f) + 1.0f) * 0.5f;
  float iB2 = ((w2.y * 2.0f - 1.0f) + 1.0f) * 0.5f;

  unsigned ka = Kl[0], kb = Kl[1];
  for (int t = 0; t < 200; ++t) {
    unsigned kan = Kl[2 * t + 2], kbn = Kl[2 * t + 3];  // prefetch (pad-safe)
    float nA0 = noise_at(ka, kb, base);
    float nB0 = noise_at(ka, kb, base + 1u);
    float nA1 = noise_at(ka, kb, base + (unsigned)HW);
    float nB1 = noise_at(ka, kb, base + (unsigned)HW + 1u);
    float nA2 = noise_at(ka, kb, base + 2u * (unsigned)HW);
    float nB2 = noise_at(ka, kb, base + 2u * (unsigned)HW + 1u);
    xA0 = clip1(xA0 + nA0); xA1 = clip1(xA1 + nA1); xA2 = clip1(xA2 + nA2);
    xB0 = clip1(xB0 + nB0); xB1 = clip1(xB1 + nB1); xB2 = clip1(xB2 + nB2);
    float dA0 = (xA0 + 1.0f) * 0.5f - iA0;
    float dA1 = (xA1 + 1.0f) * 0.5f - iA1;
    float dA2 = (xA2 + 1.0f) * 0.5f - iA2;
    float dB0 = (xB0 + 1.0f) * 0.5f - iB0;
    float dB1 = (xB1 + 1.0f) * 0.5f - iB1;
    float dB2 = (xB2 + 1.0f) * 0.5f - iB2;
    float sA = s0 * rsq_f(dA0 * dA0 + dA1 * dA1 + dA2 * dA2 + EPS_F);
    float sB = s0 * rsq_f(dB0 * dB0 + dB1 * dB1 + dB2 * dB2 + EPS_F);
    xA0 = upd(xA0, dA0 * sA); xA1 = upd(xA1, dA1 * sA); xA2 = upd(xA2, dA2 * sA);
    xB0 = upd(xB0, dB0 * sB); xB1 = upd(xB1, dB1 * sB); xB2 = upd(xB2, dB2 * sB);
    ka = kan; kb = kbn;
  }
  float* outI = out + OUT_IMG_OFF + b * 3 * HW + p;
  *(float2*)(outI)          = make_float2((xA0 + 1.0f) * 0.5f, (xB0 + 1.0f) * 0.5f);
  *(float2*)(outI + HW)     = make_float2((xA1 + 1.0f) * 0.5f, (xB1 + 1.0f) * 0.5f);
  *(float2*)(outI + 2 * HW) = make_float2((xA2 + 1.0f) * 0.5f, (xB2 + 1.0f) * 0.5f);
}

__device__ __forceinline__ void block_acc2(double v0, double v1, double* a0, double* a1) {
  for (int off = 32; off > 0; off >>= 1) {
    v0 += __shfl_down(v0, off, 64);
    v1 += __shfl_down(v1, off, 64);
  }
  __shared__ double s0m[4], s1m[4];
  int lane = threadIdx.x & 63, wv = threadIdx.x >> 6;
  if (lane == 0) { s0m[wv] = v0; s1m[wv] = v1; }
  __syncthreads();
  if (threadIdx.x == 0) {
    atomicAdd(a0, s0m[0] + s0m[1] + s0m[2] + s0m[3]);
    atomicAdd(a1, s1m[0] + s1m[1] + s1m[2] + s1m[3]);
  }
}

// 96 blocks per batch, each covering 8 contiguous 256-px chunks
__global__ __launch_bounds__(256) void k_pos_energy(const float* __restrict__ t1,
    const float* __restrict__ in1, const float* __restrict__ in2,
    double* __restrict__ acc) {
  int blk = blockIdx.x;
  int b = blk / 96;
  int local = blk - b * 96;
  const float* T0 = t1 + b * 2 * HW;
  const float* T1 = T0 + HW;
  const float* I1 = in1 + b * 3 * HW;
  const float* I2 = in2 + b * 3 * HW;
  double data = 0.0, smooth = 0.0;
  for (int it = 0; it < 8; ++it) {
    int p = (local * 8 + it) * 256 + threadIdx.x;
    int h = p >> 9, w = p & 511;
    float f00 = (T0[p] / 80.0f) * 80.0f;     // mirror (t/80)*80 roundtrip
    float f10 = (T1[p] / 80.0f) * 80.0f;
    float dx0 = 0, dx1 = 0, dy0 = 0, dy1 = 0;
    if (w < 511) { dx0 = (T0[p+1]/80.0f)*80.0f - f00;  dx1 = (T1[p+1]/80.0f)*80.0f - f10; }
    if (h < 383) { dy0 = (T0[p+WW]/80.0f)*80.0f - f00; dy1 = (T1[p+WW]/80.0f)*80.0f - f10; }
    smooth += (double)sqrtf(dx0*dx0 + dx1*dx1 + dy0*dy0 + dy1*dy1 + EPS_F);
    float d0 = ((I1[p]*2.0f-1.0f)+1.0f)*0.5f        - ((I2[p]*2.0f-1.0f)+1.0f)*0.5f;
    float d1 = ((I1[p+HW]*2.0f-1.0f)+1.0f)*0.5f     - ((I2[p+HW]*2.0f-1.0f)+1.0f)*0.5f;
    float d2 = ((I1[p+2*HW]*2.0f-1.0f)+1.0f)*0.5f   - ((I2[p+2*HW]*2.0f-1.0f)+1.0f)*0.5f;
    data += (double)sqrtf(d0*d0 + d1*d1 + d2*d2 + EPS_F);
  }
  block_acc2(data, smooth, &acc[b], &acc[8 + b]);
}

__global__ __launch_bounds__(256) void k_neg_energy(const float* __restrict__ out,
    const float* __restrict__ in2, double* __restrict__ acc) {
  int blk = blockIdx.x;
  int b = blk / 96;
  int local = blk - b * 96;
  const float* F0 = out + OUT_FLOW_OFF + b * 2 * HW;   // already = 80*x
  const float* F1 = F0 + HW;
  const float* I = out + OUT_IMG_OFF + b * 3 * HW;     // already = (x+1)/2
  const float* I2 = in2 + b * 3 * HW;
  double data = 0.0, smooth = 0.0;
  for (int it = 0; it < 8; ++it) {
    int p = (local * 8 + it) * 256 + threadIdx.x;
    int h = p >> 9, w = p & 511;
    float f00 = F0[p], f10 = F1[p];
    float dx0 = 0, dx1 = 0, dy0 = 0, dy1 = 0;
    if (w < 511) { dx0 = F0[p + 1] - f00;  dx1 = F1[p + 1] - f10; }
    if (h < 383) { dy0 = F0[p + WW] - f00; dy1 = F1[p + WW] - f10; }
    smooth += (double)sqrtf(dx0*dx0 + dx1*dx1 + dy0*dy0 + dy1*dy1 + EPS_F);
    float d0 = I[p]        - ((I2[p]*2.0f-1.0f)+1.0f)*0.5f;
    float d1 = I[p+HW]     - ((I2[p+HW]*2.0f-1.0f)+1.0f)*0.5f;
    float d2 = I[p+2*HW]   - ((I2[p+2*HW]*2.0f-1.0f)+1.0f)*0.5f;
    data += (double)sqrtf(d0*d0 + d1*d1 + d2*d2 + EPS_F);
  }
  block_acc2(data, smooth, &acc[16 + b], &acc[24 + b]);
}

__global__ void k_finalize(const double* __restrict__ acc,
                           const float* __restrict__ lw, float* __restrict__ out) {
  int t = threadIdx.x;
  if (t < 16) {
    int b = t & 7, neg = t >> 3;
    double data   = acc[neg * 16 + b];
    double smooth = acc[neg * 16 + 8 + b];
    double e0 = exp((double)lw[0]), e1 = exp((double)lw[1]);
    out[t] = (float)((e0 * data + e1 * smooth) / 196608.0);
  }
}

extern "C" void kernel_launch(void* const* d_in, const int* in_sizes, int n_in,
                              void* d_out, int out_size, void* d_ws, size_t ws_size,
                              hipStream_t stream) {
  const float* t1  = (const float*)d_in[0];
  const float* in1 = (const float*)d_in[1];
  const float* in2 = (const float*)d_in[2];
  const float* init = (const float*)d_in[3];
  const float* lw  = (const float*)d_in[4];
  float* out = (float*)d_out;

  double* acc = (double*)d_ws;                          // 32 doubles @ 0
  float* sw = (float*)((char*)d_ws + 256);              // 2 floats   @ 256
  unsigned* Kg = (unsigned*)((char*)d_ws + 512);        // 404 u32    @ 512
  float* bufFA = (float*)((char*)d_ws + 4096);          // flow ping (12.6 MB)
  size_t need = 4096 + 2 * (size_t)FLOW_N * sizeof(float);
  float* bufFB = (ws_size >= need) ? bufFA + FLOW_N
                                   : out + OUT_FLOW_OFF;  // fallback: d_out flow region

  // host-side threefry split: keys[t] = tf(0,1,0,t)  (pure integer function).
  // Static so graph-capture replays read a persistent host buffer.
  static unsigned Khost[404];
  static bool keys_done = false;
  if (!keys_done) {
    for (int t = 0; t < 200; ++t) tf2x32(0u, 1u, 0u, (unsigned)t, Khost[2*t], Khost[2*t+1]);
    Khost[400] = Khost[401] = Khost[402] = Khost[403] = 0u;
    keys_done = true;
  }
  hipMemcpyAsync(Kg, Khost, 404 * sizeof(unsigned), hipMemcpyHostToDevice, stream);

  k_init<<<1, 64, 0, stream>>>(acc, sw, lw);
  k_pos_energy<<<8 * 96, 256, 0, stream>>>(t1, in1, in2, acc);

  // ---- flow trajectory: persistent cooperative kernel (grid-stride, grid.sync
  //      per step). Sized by occupancy; falls back to per-step launches.
  static int coop_grid = -2;                   // -2 unknown, -1 unavailable
  if (coop_grid == -2) {
    int maxB = 0;
    hipError_t e = hipOccupancyMaxActiveBlocksPerMultiprocessor(&maxB, k_flow_coop, 256, 0);
    if (e == hipSuccess && maxB >= 1) {
      long g = (long)maxB * 256;               // 256 CUs on MI355X
      coop_grid = (int)(g < 1536 ? g : 1536);
    } else {
      coop_grid = -1;
    }
  }
  bool coop_done = false;
  if (coop_grid > 0) {
    void* args[] = { (void*)&init, (void*)&bufFA, (void*)&bufFB, (void*)&out,
                     (void*)&sw, (void*)&Kg };
    hipError_t e = hipLaunchCooperativeKernel((const void*)k_flow_coop,
                                              dim3(coop_grid), dim3(256),
                                              args, 0, stream);
    if (e == hipSuccess) coop_done = true;
    else coop_grid = -1;                       // remember failure, fall back
  }
  if (!coop_done) {
    k_fnoise0<<<FLOW_N / 256, 256, 0, stream>>>(init, bufFB, Khost[0], Khost[1]);
    for (int t = 0; t < 199; ++t) {
      const float* src = (t % 2 == 0) ? bufFB : bufFA;
      float* dst       = (t % 2 == 0) ? bufFA : bufFB;
      k_fstep4<false><<<NQUADS / 256, 256, 0, stream>>>(src, dst, sw,
                                                        Khost[2*t+2], Khost[2*t+3]);
    }
    k_fstep4<true><<<NQUADS / 256, 256, 0, stream>>>(bufFA, out, sw, 0u, 0u);
  }

  // ---- img trajectory: one persistent kernel, all 200 steps in registers,
  //      2 pixels per thread (exact per-value bits)
  k_img<<<8 * HW / 512, 256, 0, stream>>>(init, in2, sw, out);

  k_neg_energy<<<8 * 96, 256, 0, stream>>>(out, in2, acc);
  k_finalize<<<1, 64, 0, stream>>>(acc, lw, out);
}

// Round 4
// 4604.539 us; speedup vs baseline: 5.8767x; 5.8767x over previous
//
#include <hip/hip_runtime.h>
#include <math.h>

#define HH 384
#define WW 512
#define HW 196608            // 384*512
#define QHW 49152            // HW/4
#define CHW 983040           // 5*HW
#define NTOT 7864320         // 8*CHW
#define FLOW_N 3145728       // 8*2*HW
#define NQUADS 393216        // 8*QHW
#define OUT_FLOW_OFF 16
#define OUT_IMG_OFF (16 + FLOW_N)
#define EPS_F 1e-5f
#define EPS_S (1e-5f / 6400.0f)   // smooth-term eps in raw-x domain (S is deg-1 homog in 80x)
#define INV_HW (1.0f/196608.0f)

// single-instruction HW ops (~1 ulp); med3 == min(max(x,lo),hi) for finite x
__device__ __forceinline__ float rsq_f(float x)  { return __builtin_amdgcn_rsqf(x); }
__device__ __forceinline__ float ln_f(float x)   { return 0.69314718055994531f * __builtin_amdgcn_logf(x); }
__device__ __forceinline__ float sqrt_f(float x) { return __builtin_amdgcn_sqrtf(x); }
__device__ __forceinline__ float med3(float x, float lo, float hi) {
  return __builtin_amdgcn_fmed3f(x, lo, hi);
}

// ---- JAX threefry2x32 (bit-exact integer path), host+device ----
__host__ __device__ __forceinline__ void tf2x32(unsigned k0, unsigned k1,
                                                unsigned x0, unsigned x1,
                                                unsigned& o0, unsigned& o1) {
  const unsigned ks2 = k0 ^ k1 ^ 0x1BD11BDAu;
  x0 += k0; x1 += k1;
#define TFR(r) x0 += x1; x1 = (x1 << (r)) | (x1 >> (32 - (r))); x1 ^= x0;
  TFR(13) TFR(15) TFR(26) TFR(6)
  x0 += k1;  x1 += ks2 + 1u;
  TFR(17) TFR(29) TFR(16) TFR(24)
  x0 += ks2; x1 += k0 + 2u;
  TFR(13) TFR(15) TFR(26) TFR(6)
  x0 += k0;  x1 += k1 + 3u;
  TFR(17) TFR(29) TFR(16) TFR(24)
  x0 += k1;  x1 += ks2 + 4u;
  TFR(13) TFR(15) TFR(26) TFR(6)
  x0 += ks2; x1 += k0 + 5u;
#undef TFR
  o0 = x0; o1 = x1;
}

// bits -> NOISE_STD * sqrt(2) * erfinv(uniform(lo,1))   (JAX normal * 0.05)
__device__ __forceinline__ float noise_from_bits(unsigned bits) {
  const float LO = -0.99999994f;                    // nextafter(-1,0)
  float f = __uint_as_float((bits >> 9) | 0x3F800000u) - 1.0f;  // [0,1)
  float u = fmaxf(LO, f * 2.0f + LO);               // (hi-lo) rounds to 2.0f
  // -log1p(-u^2) via factored form (accurate near |u|~1) + HW log
  float w = -ln_f((1.0f - u) * (1.0f + u));
  float p;
  if (w < 5.0f) {
    w -= 2.5f;
    p = 2.81022636e-08f;
    p = p * w + 3.43273939e-07f;
    p = p * w + -3.5233877e-06f;
    p = p * w + -4.39150654e-06f;
    p = p * w + 0.00021858087f;
    p = p * w + -0.00125372503f;
    p = p * w + -0.00417768164f;
    p = p * w + 0.246640727f;
    p = p * w + 1.50140941f;
  } else {
    w = sqrt_f(w) - 3.0f;
    p = -0.000200214257f;
    p = p * w + 0.000100950558f;
    p = p * w + 0.00134934322f;
    p = p * w + -0.00367342844f;
    p = p * w + 0.00573950773f;
    p = p * w + -0.0076224613f;
    p = p * w + 0.00943887047f;
    p = p * w + 1.00167406f;
    p = p * w + 2.83297682f;
  }
  float z = 1.4142135623730951f * (p * u);
  return 0.05f * z;
}

__device__ __forceinline__ float upd(float x, float g) {
  g = med3(g, -0.03f, 0.03f);
  return med3(x - 10.0f * g, -1.0f, 1.0f);
}

// EXACT JAX partitionable-threefry bits: counter = (0, idx), output o0^o1.
__device__ __forceinline__ float noise_at(unsigned ka, unsigned kb, unsigned idx) {
  unsigned o0, o1;
  tf2x32(ka, kb, 0u, idx, o0, o1);
  return noise_from_bits(o0 ^ o1);
}

__device__ __forceinline__ float clip1(float x) { return med3(x, -1.0f, 1.0f); }

// add noise to 4 results and store as float4 (non-final path)
__device__ __forceinline__ void noise_store4(float* dst, const float xn[4],
                                             unsigned ka, unsigned kb, unsigned idx0) {
  float r[4];
#pragma unroll
  for (int j = 0; j < 4; ++j)
    r[j] = clip1(xn[j] + noise_at(ka, kb, idx0 + (unsigned)j));
  *(float4*)dst = make_float4(r[0], r[1], r[2], r[3]);
}

// ---- kernels ----
__global__ void k_init(double* acc, float* sw, const float* lw) {
  int t = threadIdx.x;
  if (t < 32) acc[t] = 0.0;
  if (t == 32) {
    sw[0] = expf(lw[0]) * INV_HW * 0.5f;    // data-term scale
    sw[1] = expf(lw[1]) * INV_HW * 80.0f;   // smooth-term scale (incl d(flow)/dx = 80)
  }
}

// flow noise_0: compact (B,2,H,W) buffer, noise indexed in original 5-ch layout
__global__ __launch_bounds__(256) void k_fnoise0(const float* __restrict__ init,
    float* __restrict__ Y, unsigned ka, unsigned kb) {
  int e = blockIdx.x * 256 + threadIdx.x;    // [0, FLOW_N)
  int b = e / (2 * HW);
  int r = e - b * 2 * HW;
  int orig = b * CHW + r;                    // original element index (channels 0..1)
  Y[e] = clip1(init[orig] + noise_at(ka, kb, (unsigned)orig));
}

// flow grad step, 4 px/thread along w -> 1536 blocks = ONE residency round.
// XCD-slab swizzle: HW round-robins blocks across 8 XCDs (blk%8); remap so
// XCD x owns batch x entirely -> ping-pong slab (3.1 MB) fits its 4 MiB L2
// and all stencil halo traffic is XCD-local. Work remap only: bit-exact.
template <bool FINAL>
__global__ __launch_bounds__(256) void k_fstep4(const float* __restrict__ X,
    float* __restrict__ Y, const float* __restrict__ sw,
    unsigned ka, unsigned kb) {
  int wb = (blockIdx.x & 7) * (NQUADS / 256 / 8) + (blockIdx.x >> 3);
  int tid = wb * 256 + threadIdx.x;           // [0, NQUADS)
  int b = tid / QHW;
  int q = tid - b * QHW;
  int p = q * 4;                              // pixel base, multiple of 4
  int h = p >> 9, w = p & 511;
  float s1v = sw[1];
  const float* F0 = X + b * 2 * HW;
  const float* F1 = F0 + HW;
  const bool wpos = (w > 0), wend = (w == 508);
  const bool hpos = (h > 0), hlast = (h == 383);

  // ---- stencil values; cf[c][4] duplicated at right edge so dx=0 ----
  float cf[2][5], fm1[2], dw[2][4], dwm1[2], uf[2][5];
  {
    float4 a0 = *(const float4*)(F0 + p);
    float4 a1 = *(const float4*)(F1 + p);
    cf[0][0]=a0.x; cf[0][1]=a0.y; cf[0][2]=a0.z; cf[0][3]=a0.w;
    cf[1][0]=a1.x; cf[1][1]=a1.y; cf[1][2]=a1.z; cf[1][3]=a1.w;
    cf[0][4] = wend ? cf[0][3] : F0[p + 4];
    cf[1][4] = wend ? cf[1][3] : F1[p + 4];
    fm1[0] = wpos ? F0[p - 1] : cf[0][0];
    fm1[1] = wpos ? F1[p - 1] : cf[1][0];
    if (!hlast) {
      float4 d0 = *(const float4*)(F0 + p + WW);
      float4 d1 = *(const float4*)(F1 + p + WW);
      dw[0][0]=d0.x; dw[0][1]=d0.y; dw[0][2]=d0.z; dw[0][3]=d0.w;
      dw[1][0]=d1.x; dw[1][1]=d1.y; dw[1][2]=d1.z; dw[1][3]=d1.w;
      dwm1[0] = wpos ? F0[p + WW - 1] : fm1[0];
      dwm1[1] = wpos ? F1[p + WW - 1] : fm1[1];
    } else {
#pragma unroll
      for (int c = 0; c < 2; ++c) {
        for (int j = 0; j < 4; ++j) dw[c][j] = cf[c][j];   // dy = 0
        dwm1[c] = fm1[c];
      }
    }
    if (hpos) {
      float4 u0 = *(const float4*)(F0 + p - WW);
      float4 u1 = *(const float4*)(F1 + p - WW);
      uf[0][0]=u0.x; uf[0][1]=u0.y; uf[0][2]=u0.z; uf[0][3]=u0.w;
      uf[1][0]=u1.x; uf[1][1]=u1.y; uf[1][2]=u1.z; uf[1][3]=u1.w;
      uf[0][4] = wend ? uf[0][3] : F0[p - WW + 4];
      uf[1][4] = wend ? uf[1][3] : F1[p - WW + 4];
    } else {
#pragma unroll
      for (int c = 0; c < 2; ++c)
        for (int j = 0; j < 5; ++j) uf[c][j] = cf[c][j];   // unused (masked by hpos)
    }
  }

  // ---- shared S sites: SL = S(h,w-1); Sc[j] = S(h,w+j); Su[j] = S(h-1,w+j) ----
  float dxc[2][4], dyc[2][4], invSc[4], dxu[2][4], dyu[2][4], invSu[4];
  float dxl[2], dyl[2], invSL;
#pragma unroll
  for (int j = 0; j < 4; ++j) {
#pragma unroll
    for (int c = 0; c < 2; ++c) {
      dxc[c][j] = cf[c][j + 1] - cf[c][j];
      dyc[c][j] = dw[c][j] - cf[c][j];
      dxu[c][j] = uf[c][j + 1] - uf[c][j];
      dyu[c][j] = cf[c][j] - uf[c][j];
    }
    invSc[j] = rsq_f(dxc[0][j]*dxc[0][j] + dxc[1][j]*dxc[1][j]
                   + dyc[0][j]*dyc[0][j] + dyc[1][j]*dyc[1][j] + EPS_S);
    invSu[j] = rsq_f(dxu[0][j]*dxu[0][j] + dxu[1][j]*dxu[1][j]
                   + dyu[0][j]*dyu[0][j] + dyu[1][j]*dyu[1][j] + EPS_S);
  }
  dxl[0] = cf[0][0] - fm1[0];  dxl[1] = cf[1][0] - fm1[1];
  dyl[0] = dwm1[0] - fm1[0];   dyl[1] = dwm1[1] - fm1[1];
  invSL = rsq_f(dxl[0]*dxl[0] + dxl[1]*dxl[1]
              + dyl[0]*dyl[0] + dyl[1]*dyl[1] + EPS_S);

  // ---- grads + update ----
  float xnF[2][4];
#pragma unroll
  for (int j = 0; j < 4; ++j) {
#pragma unroll
    for (int c = 0; c < 2; ++c) {
      float g = -(dxc[c][j] + dyc[c][j]) * invSc[j];
      if (j == 0) { if (wpos) g += dxl[c] * invSL; }
      else        { g += dxc[c][j - 1] * invSc[j - 1]; }
      if (hpos)   { g += dyu[c][j] * invSu[j]; }
      xnF[c][j] = upd(cf[c][j], g * s1v);
    }
  }

  // ---- noise + store (or final transform) ----
  if (!FINAL) {
    int nbase = b * CHW + p;                 // noise index in original 5-ch layout
    int sb = b * 2 * HW + p;                 // compact store index
    noise_store4(Y + sb,      xnF[0], ka, kb, (unsigned)nbase);
    noise_store4(Y + sb + HW, xnF[1], ka, kb, (unsigned)(nbase + HW));
  } else {
    float* outF = Y + OUT_FLOW_OFF + b * 2 * HW;
    *(float4*)(outF + p)      = make_float4(xnF[0][0]*80.f, xnF[0][1]*80.f,
                                            xnF[0][2]*80.f, xnF[0][3]*80.f);
    *(float4*)(outF + HW + p) = make_float4(xnF[1][0]*80.f, xnF[1][1]*80.f,
                                            xnF[1][2]*80.f, xnF[1][3]*80.f);
  }
}

// img channels: per-pixel independent 200-step recurrence, state in registers.
// 2 pixels/thread -> 6 independent threefry chains (ILP); bits per value EXACT
// (tf(key,0,idx), o0^o1). launch_bounds(256,4): 128-VGPR budget so the chains
// actually get registers (round-0 compiled to 12 VGPR = fully serialized).
__global__ __launch_bounds__(256, 4) void k_img(const float* __restrict__ init,
    const float* __restrict__ in2, const float* __restrict__ sw,
    float* __restrict__ out) {
  __shared__ unsigned Kl[404];
  int tid = threadIdx.x;
  if (tid < 202) {                            // split(key(1),200): tf(0,1,0,t); 2 pad
    unsigned a, bb;
    tf2x32(0u, 1u, 0u, (unsigned)tid, a, bb);
    Kl[2 * tid] = a; Kl[2 * tid + 1] = bb;
  }
  __syncthreads();
  int g = blockIdx.x * 256 + tid;             // [0, 8*HW/2)
  int b = g / (HW / 2);
  int p = (g - b * (HW / 2)) * 2;             // even pixel; pair = (p, p+1)
  float s0 = sw[0];
  unsigned base = (unsigned)(b * CHW + 2 * HW + p);   // channel-2 noise index, pixel A

  float2 v0 = *(const float2*)(init + base);
  float2 v1 = *(const float2*)(init + base + HW);
  float2 v2 = *(const float2*)(init + base + 2 * HW);
  float xA0 = v0.x, xA1 = v1.x, xA2 = v2.x;
  float xB0 = v0.y, xB1 = v1.y, xB2 = v2.y;

  const float* I2 = in2 + b * 3 * HW + p;
  float2 w0 = *(const float2*)(I2);
  float2 w1 = *(const float2*)(I2 + HW);
  float2 w2 = *(const float2*)(I2 + 2 * HW);
  float iA0 = ((w0.x * 2.0f - 1.0f) + 1.0f) * 0.5f;
  float iB0 = ((w0.y * 2.0f - 1.0f) + 1.0f) * 0.5f;
  float iA1 = ((w1.x * 2.0f - 1.0f) + 1.0f) * 0.5f;
  float iB1 = ((w1.y * 2.0f - 1.0f) + 1.0f) * 0.5f;
  float iA2 = ((w2.x * 2.0f - 1.0f) + 1.0f) * 0.5f;
  float iB2 = ((w2.y * 2.0f - 1.0f) + 1.0f) * 0.5f;

  unsigned ka = Kl[0], kb = Kl[1];
  for (int t = 0; t < 200; ++t) {
    unsigned kan = Kl[2 * t + 2], kbn = Kl[2 * t + 3];  // prefetch (pad-safe)
    float nA0 = noise_at(ka, kb, base);
    float nB0 = noise_at(ka, kb, base + 1u);
    float nA1 = noise_at(ka, kb, base + (unsigned)HW);
    float nB1 = noise_at(ka, kb, base + (unsigned)HW + 1u);
    float nA2 = noise_at(ka, kb, base + 2u * (unsigned)HW);
    float nB2 = noise_at(ka, kb, base + 2u * (unsigned)HW + 1u);
    xA0 = clip1(xA0 + nA0); xA1 = clip1(xA1 + nA1); xA2 = clip1(xA2 + nA2);
    xB0 = clip1(xB0 + nB0); xB1 = clip1(xB1 + nB1); xB2 = clip1(xB2 + nB2);
    float dA0 = (xA0 + 1.0f) * 0.5f - iA0;
    float dA1 = (xA1 + 1.0f) * 0.5f - iA1;
    float dA2 = (xA2 + 1.0f) * 0.5f - iA2;
    float dB0 = (xB0 + 1.0f) * 0.5f - iB0;
    float dB1 = (xB1 + 1.0f) * 0.5f - iB1;
    float dB2 = (xB2 + 1.0f) * 0.5f - iB2;
    float sA = s0 * rsq_f(dA0 * dA0 + dA1 * dA1 + dA2 * dA2 + EPS_F);
    float sB = s0 * rsq_f(dB0 * dB0 + dB1 * dB1 + dB2 * dB2 + EPS_F);
    xA0 = upd(xA0, dA0 * sA); xA1 = upd(xA1, dA1 * sA); xA2 = upd(xA2, dA2 * sA);
    xB0 = upd(xB0, dB0 * sB); xB1 = upd(xB1, dB1 * sB); xB2 = upd(xB2, dB2 * sB);
    ka = kan; kb = kbn;
  }
  float* outI = out + OUT_IMG_OFF + b * 3 * HW + p;
  *(float2*)(outI)          = make_float2((xA0 + 1.0f) * 0.5f, (xB0 + 1.0f) * 0.5f);
  *(float2*)(outI + HW)     = make_float2((xA1 + 1.0f) * 0.5f, (xB1 + 1.0f) * 0.5f);
  *(float2*)(outI + 2 * HW) = make_float2((xA2 + 1.0f) * 0.5f, (xB2 + 1.0f) * 0.5f);
}

__device__ __forceinline__ void block_acc2(double v0, double v1, double* a0, double* a1) {
  for (int off = 32; off > 0; off >>= 1) {
    v0 += __shfl_down(v0, off, 64);
    v1 += __shfl_down(v1, off, 64);
  }
  __shared__ double s0m[4], s1m[4];
  int lane = threadIdx.x & 63, wv = threadIdx.x >> 6;
  if (lane == 0) { s0m[wv] = v0; s1m[wv] = v1; }
  __syncthreads();
  if (threadIdx.x == 0) {
    atomicAdd(a0, s0m[0] + s0m[1] + s0m[2] + s0m[3]);
    atomicAdd(a1, s1m[0] + s1m[1] + s1m[2] + s1m[3]);
  }
}

// 96 blocks per batch, each covering 8 contiguous 256-px chunks
__global__ __launch_bounds__(256) void k_pos_energy(const float* __restrict__ t1,
    const float* __restrict__ in1, const float* __restrict__ in2,
    double* __restrict__ acc) {
  int blk = blockIdx.x;
  int b = blk / 96;
  int local = blk - b * 96;
  const float* T0 = t1 + b * 2 * HW;
  const float* T1 = T0 + HW;
  const float* I1 = in1 + b * 3 * HW;
  const float* I2 = in2 + b * 3 * HW;
  double data = 0.0, smooth = 0.0;
  for (int it = 0; it < 8; ++it) {
    int p = (local * 8 + it) * 256 + threadIdx.x;
    int h = p >> 9, w = p & 511;
    float f00 = (T0[p] / 80.0f) * 80.0f;     // mirror (t/80)*80 roundtrip
    float f10 = (T1[p] / 80.0f) * 80.0f;
    float dx0 = 0, dx1 = 0, dy0 = 0, dy1 = 0;
    if (w < 511) { dx0 = (T0[p+1]/80.0f)*80.0f - f00;  dx1 = (T1[p+1]/80.0f)*80.0f - f10; }
    if (h < 383) { dy0 = (T0[p+WW]/80.0f)*80.0f - f00; dy1 = (T1[p+WW]/80.0f)*80.0f - f10; }
    smooth += (double)sqrtf(dx0*dx0 + dx1*dx1 + dy0*dy0 + dy1*dy1 + EPS_F);
    float d0 = ((I1[p]*2.0f-1.0f)+1.0f)*0.5f        - ((I2[p]*2.0f-1.0f)+1.0f)*0.5f;
    float d1 = ((I1[p+HW]*2.0f-1.0f)+1.0f)*0.5f     - ((I2[p+HW]*2.0f-1.0f)+1.0f)*0.5f;
    float d2 = ((I1[p+2*HW]*2.0f-1.0f)+1.0f)*0.5f   - ((I2[p+2*HW]*2.0f-1.0f)+1.0f)*0.5f;
    data += (double)sqrtf(d0*d0 + d1*d1 + d2*d2 + EPS_F);
  }
  block_acc2(data, smooth, &acc[b], &acc[8 + b]);
}

__global__ __launch_bounds__(256) void k_neg_energy(const float* __restrict__ out,
    const float* __restrict__ in2, double* __restrict__ acc) {
  int blk = blockIdx.x;
  int b = blk / 96;
  int local = blk - b * 96;
  const float* F0 = out + OUT_FLOW_OFF + b * 2 * HW;   // already = 80*x
  const float* F1 = F0 + HW;
  const float* I = out + OUT_IMG_OFF + b * 3 * HW;     // already = (x+1)/2
  const float* I2 = in2 + b * 3 * HW;
  double data = 0.0, smooth = 0.0;
  for (int it = 0; it < 8; ++it) {
    int p = (local * 8 + it) * 256 + threadIdx.x;
    int h = p >> 9, w = p & 511;
    float f00 = F0[p], f10 = F1[p];
    float dx0 = 0, dx1 = 0, dy0 = 0, dy1 = 0;
    if (w < 511) { dx0 = F0[p + 1] - f00;  dx1 = F1[p + 1] - f10; }
    if (h < 383) { dy0 = F0[p + WW] - f00; dy1 = F1[p + WW] - f10; }
    smooth += (double)sqrtf(dx0*dx0 + dx1*dx1 + dy0*dy0 + dy1*dy1 + EPS_F);
    float d0 = I[p]        - ((I2[p]*2.0f-1.0f)+1.0f)*0.5f;
    float d1 = I[p+HW]     - ((I2[p+HW]*2.0f-1.0f)+1.0f)*0.5f;
    float d2 = I[p+2*HW]   - ((I2[p+2*HW]*2.0f-1.0f)+1.0f)*0.5f;
    data += (double)sqrtf(d0*d0 + d1*d1 + d2*d2 + EPS_F);
  }
  block_acc2(data, smooth, &acc[16 + b], &acc[24 + b]);
}

__global__ void k_finalize(const double* __restrict__ acc,
                           const float* __restrict__ lw, float* __restrict__ out) {
  int t = threadIdx.x;
  if (t < 16) {
    int b = t & 7, neg = t >> 3;
    double data   = acc[neg * 16 + b];
    double smooth = acc[neg * 16 + 8 + b];
    double e0 = exp((double)lw[0]), e1 = exp((double)lw[1]);
    out[t] = (float)((e0 * data + e1 * smooth) / 196608.0);
  }
}

extern "C" void kernel_launch(void* const* d_in, const int* in_sizes, int n_in,
                              void* d_out, int out_size, void* d_ws, size_t ws_size,
                              hipStream_t stream) {
  const float* t1  = (const float*)d_in[0];
  const float* in1 = (const float*)d_in[1];
  const float* in2 = (const float*)d_in[2];
  const float* init = (const float*)d_in[3];
  const float* lw  = (const float*)d_in[4];
  float* out = (float*)d_out;

  double* acc = (double*)d_ws;                          // 32 doubles
  float* sw = (float*)((char*)d_ws + 256);              // 2 floats
  float* bufFA = (float*)((char*)d_ws + 2048);          // flow ping (12.6 MB)
  size_t need = 2048 + 2 * (size_t)FLOW_N * sizeof(float);
  float* bufFB = (ws_size >= need) ? bufFA + FLOW_N
                                   : out + OUT_FLOW_OFF;  // fallback: d_out flow region

  // host-side threefry split: keys[t] = tf(0,1,0,t)  (pure integer function)
  unsigned K0[200], K1[200];
  for (int t = 0; t < 200; ++t) tf2x32(0u, 1u, 0u, (unsigned)t, K0[t], K1[t]);

  k_init<<<1, 64, 0, stream>>>(acc, sw, lw);
  k_pos_energy<<<8 * 96, 256, 0, stream>>>(t1, in1, in2, acc);

  // ---- flow trajectory: noise_0, then 199 grad(+noise) steps, then final grad.
  //      Parity: noise0 -> bufFB; t even FB->FA, t odd FA->FB; t=198 even -> FA;
  //      FINAL reads bufFA (never aliases out).
  k_fnoise0<<<FLOW_N / 256, 256, 0, stream>>>(init, bufFB, K0[0], K1[0]);
  for (int t = 0; t < 199; ++t) {
    const float* src = (t % 2 == 0) ? bufFB : bufFA;
    float* dst       = (t % 2 == 0) ? bufFA : bufFB;
    k_fstep4<false><<<NQUADS / 256, 256, 0, stream>>>(src, dst, sw,
                                                      K0[t + 1], K1[t + 1]);
  }
  k_fstep4<true><<<NQUADS / 256, 256, 0, stream>>>(bufFA, out, sw, 0u, 0u);

  // ---- img trajectory: one persistent kernel, all 200 steps in registers,
  //      2 pixels per thread (exact per-value bits)
  k_img<<<8 * HW / 512, 256, 0, stream>>>(init, in2, sw, out);

  k_neg_energy<<<8 * 96, 256, 0, stream>>>(out, in2, acc);
  k_finalize<<<1, 64, 0, stream>>>(acc, lw, out);
}